// Round 3
// baseline (11272.339 us; speedup 1.0000x reference)
//
#include <hip/hip_runtime.h>
#include <cstdint>

typedef _Float16 half2_t __attribute__((ext_vector_type(2)));
typedef _Float16 half8_t __attribute__((ext_vector_type(8)));
typedef float    floatx4 __attribute__((ext_vector_type(4)));

// ---------------- workspace layout (bytes) ----------------
#define OFF_BIAS  0ull
#define SZ_BIAS   (1536ull*4)                  // b_ih + b_hh(r,z) folded, f32
#define OFF_GI    6144ull                      // gi f16 [2][32768][768] (~100.7 MB)

// ---------------- prep: bias fold only ----------------
__global__ void k_prep(const float* __restrict__ bih1, const float* __restrict__ bih2,
                       const float* __restrict__ bhh1, const float* __restrict__ bhh2,
                       float* __restrict__ biascat) {
    int q3 = blockIdx.x * 256 + threadIdx.x;
    if (q3 < 1536) {
        // fold b_ih (all gates) + b_hh (r,z only; n-gate's b_hh is inside r*(...))
        int dir = q3 >= 768;  int j = q3 - dir*768;
        const float* bi = dir ? bih2 : bih1;
        const float* bh = dir ? bhh2 : bhh1;
        biascat[q3] = bi[j] + (j < 512 ? bh[j] : 0.f);
    }
}

// ---------------- gi GEMM: (32768 x 512) @ (512 x 1536) via f16 MFMA ----------------
// SOURCE-IDENTICAL to round 2 (carries all MFMA layout assumptions under test).
__device__ __forceinline__ half8_t cvt8(float4 a, float4 b) {
    half8_t r;
    r[0] = (_Float16)a.x; r[1] = (_Float16)a.y; r[2] = (_Float16)a.z; r[3] = (_Float16)a.w;
    r[4] = (_Float16)b.x; r[5] = (_Float16)b.y; r[6] = (_Float16)b.z; r[7] = (_Float16)b.w;
    return r;
}

__global__ __launch_bounds__(256) void k_gemm(const float* __restrict__ x,
                                              const float* __restrict__ Wih1,
                                              const float* __restrict__ Wih2,
                                              const float* __restrict__ bias,
                                              _Float16* __restrict__ gi) {
    __shared__ __align__(16) _Float16 As[128*32];   // [m][k], LD=32
    __shared__ __align__(16) _Float16 Bs[256*32];   // [n][k], LD=32
    const int tid = threadIdx.x;
    const int m0 = blockIdx.x * 128;
    const int n0 = blockIdx.y * 256;                // 768 = 3*256: no dir straddle
    const int lane = tid & 63, wave = tid >> 6;
    const int wr = wave >> 1, wc = wave & 1;        // 2x2 waves: 64M x 128N each
    floatx4 acc[4][8];
#pragma unroll
    for (int i = 0; i < 4; ++i)
#pragma unroll
        for (int j = 0; j < 8; ++j) acc[i][j] = (floatx4)0.f;

    const float* Wsrc = (n0 < 768) ? Wih1 : Wih2;
    const int nl = (n0 < 768) ? n0 : (n0 - 768);
    const int ar = tid >> 1, ah = (tid & 1) * 16;   // A: 2 threads/row, 16 cols each
    const float* Ag = x + (size_t)(m0 + ar)*512 + ah;
    const float* Bg = Wsrc + (size_t)(nl + tid)*512; // B: 1 thread/row, 32 cols
    _Float16* Aw = As + ar*32 + ah;
    _Float16* Bw = Bs + tid*32;
    const int aoff = (wr*64  + (lane & 15))*32 + (lane >> 4)*8;
    const int boff = (wc*128 + (lane & 15))*32 + (lane >> 4)*8;

    for (int kt = 0; kt < 16; ++kt) {
        const int ko = kt*32;
        float4 a0 = *(const float4*)(Ag + ko);
        float4 a1 = *(const float4*)(Ag + ko + 4);
        float4 a2 = *(const float4*)(Ag + ko + 8);
        float4 a3 = *(const float4*)(Ag + ko + 12);
        float4 b0 = *(const float4*)(Bg + ko);
        float4 b1 = *(const float4*)(Bg + ko + 4);
        float4 b2 = *(const float4*)(Bg + ko + 8);
        float4 b3 = *(const float4*)(Bg + ko + 12);
        float4 b4 = *(const float4*)(Bg + ko + 16);
        float4 b5 = *(const float4*)(Bg + ko + 20);
        float4 b6 = *(const float4*)(Bg + ko + 24);
        float4 b7 = *(const float4*)(Bg + ko + 28);
        __syncthreads();                       // prev tile's LDS reads complete
        *(half8_t*)(Aw)      = cvt8(a0, a1);
        *(half8_t*)(Aw + 8)  = cvt8(a2, a3);
        *(half8_t*)(Bw)      = cvt8(b0, b1);
        *(half8_t*)(Bw + 8)  = cvt8(b2, b3);
        *(half8_t*)(Bw + 16) = cvt8(b4, b5);
        *(half8_t*)(Bw + 24) = cvt8(b6, b7);
        __syncthreads();
        half8_t af[4], bf[8];
#pragma unroll
        for (int f = 0; f < 4; ++f) af[f] = *(const half8_t*)(As + aoff + f*512);
#pragma unroll
        for (int f = 0; f < 8; ++f) bf[f] = *(const half8_t*)(Bs + boff + f*512);
#pragma unroll
        for (int i = 0; i < 4; ++i)
#pragma unroll
            for (int j = 0; j < 8; ++j)
                acc[i][j] = __builtin_amdgcn_mfma_f32_16x16x32_f16(af[i], bf[j], acc[i][j], 0, 0, 0);
    }
    // epilogue: +bias, f16, split into gi[dir][row][col]
#pragma unroll
    for (int i = 0; i < 4; ++i) {
#pragma unroll
        for (int j = 0; j < 8; ++j) {
            int col = n0 + wc*128 + j*16 + (lane & 15);
            float bv = bias[col];
            int dir = col >= 768;
            size_t gib = (size_t)dir * 25165824ull + (size_t)(col - dir*768);
#pragma unroll
            for (int q = 0; q < 4; ++q) {
                int row = m0 + wr*64 + i*16 + (lane >> 4)*4 + q;
                gi[gib + (size_t)row*768] = (_Float16)(acc[i][j][q] + bv);
            }
        }
    }
}

// ---------------- BISECT: naive f32 recurrent kernel ----------------
// 1 WG per (direction, batch). Thread c owns hidden column c. W_hh read raw
// from global (L2-resident), f32 FMA dots, h in f32 LDS, libm activations.
__global__ void k_rnn_naive(const float* __restrict__ Whh1, const float* __restrict__ Whh2,
                            const _Float16* __restrict__ gi, const float* __restrict__ mask,
                            const float* __restrict__ bhh1, const float* __restrict__ bhh2,
                            float* __restrict__ outp) {
    __shared__ float hs[256];
    const int c   = threadIdx.x;                 // 0..255
    const int bid = blockIdx.x;                  // 0..127
    const int dir = bid >> 6, b = bid & 63;
    const float* W  = dir ? Whh2 : Whh1;         // (768, 256) row-major
    const float  bhn = (dir ? bhh2 : bhh1)[512 + c];
    const float* wr_ = W + (size_t)c*256;        // r-gate row c
    const float* wz_ = W + (size_t)(c + 256)*256;
    const float* wn_ = W + (size_t)(c + 512)*256;

    hs[c] = 0.f;
    float h_c = 0.f;
    __syncthreads();

    const _Float16* gb = gi + (size_t)dir * 25165824ull + c;

    for (int s = 0; s < 512; ++s) {
        const int t = dir ? (511 - s) : s;
        const _Float16* gp = gb + (size_t)(t*64 + b)*768;
        float g0 = (float)gp[0];                 // i_r (+b_ih_r+b_hh_r folded)
        float g1 = (float)gp[256];               // i_z (+b_ih_z+b_hh_z folded)
        float g2 = (float)gp[512];               // i_n (+b_ih_n folded)
        float mv = mask[t*64 + b];

        float ghr = 0.f, ghz = 0.f, ghn = 0.f;
#pragma unroll 8
        for (int k = 0; k < 256; ++k) {
            float hk = hs[k];
            ghr += wr_[k] * hk;
            ghz += wz_[k] * hk;
            ghn += wn_[k] * hk;
        }
        float r  = 1.f / (1.f + expf(-(g0 + ghr)));
        float z  = 1.f / (1.f + expf(-(g1 + ghz)));
        float nt = tanhf(g2 + r * (ghn + bhn));
        float ht = (1.f - z) * nt + z * h_c;
        float hm = mv * ht + (1.f - mv) * h_c;

        __syncthreads();                         // all reads of hs done
        hs[c] = hm;
        h_c = hm;
        outp[(size_t)(t*64 + b)*512 + dir*256 + c] = mv * ht;
        __syncthreads();                         // writes visible for next step
    }
    outp[16777216u + dir*16384 + b*256 + c] = h_c;   // hidden[dir][b][c]
}

// ---------------- launch ----------------
extern "C" void kernel_launch(void* const* d_in, const int* in_sizes, int n_in,
                              void* d_out, int out_size, void* d_ws, size_t ws_size,
                              hipStream_t stream) {
    const float* x    = (const float*)d_in[0];
    const float* mask = (const float*)d_in[1];
    const float* Wih1 = (const float*)d_in[2];
    const float* Whh1 = (const float*)d_in[3];
    const float* bih1 = (const float*)d_in[4];
    const float* bhh1 = (const float*)d_in[5];
    const float* Wih2 = (const float*)d_in[6];
    const float* Whh2 = (const float*)d_in[7];
    const float* bih2 = (const float*)d_in[8];
    const float* bhh2 = (const float*)d_in[9];
    char* ws = (char*)d_ws;
    float* biascat = (float*)(ws + OFF_BIAS);
    _Float16* gi   = (_Float16*)(ws + OFF_GI);
    float* outp = (float*)d_out;

    hipLaunchKernelGGL(k_prep, dim3(6), dim3(256), 0, stream,
                       bih1, bih2, bhh1, bhh2, biascat);
    hipLaunchKernelGGL(k_gemm, dim3(256, 6), dim3(256), 0, stream, x, Wih1, Wih2, biascat, gi);
    hipLaunchKernelGGL(k_rnn_naive, dim3(128), dim3(256), 0, stream,
                       Whh1, Whh2, gi, mask, bhh1, bhh2, outp);
}

// Round 6
// 852.098 us; speedup vs baseline: 13.2289x; 13.2289x over previous
//
#include <hip/hip_runtime.h>
#include <cstdint>

typedef _Float16 half2_t __attribute__((ext_vector_type(2)));
typedef _Float16 half8_t __attribute__((ext_vector_type(8)));
typedef float    floatx4 __attribute__((ext_vector_type(4)));

// ---------------- workspace layout (bytes) ----------------
#define OFF_BIAS  0ull
#define SZ_BIAS   (1536ull*4)                  // b_ih + b_hh(r,z) folded, f32
#define OFF_GI    6144ull                      // gi f16 [2][32768][768] (~100.7 MB)

// ---------------- prep: bias fold only (verified round 3) ----------------
__global__ void k_prep(const float* __restrict__ bih1, const float* __restrict__ bih2,
                       const float* __restrict__ bhh1, const float* __restrict__ bhh2,
                       float* __restrict__ biascat) {
    int q3 = blockIdx.x * 256 + threadIdx.x;
    if (q3 < 1536) {
        // fold b_ih (all gates) + b_hh (r,z only; n-gate's b_hh is inside r*(...))
        int dir = q3 >= 768;  int j = q3 - dir*768;
        const float* bi = dir ? bih2 : bih1;
        const float* bh = dir ? bhh2 : bhh1;
        biascat[q3] = bi[j] + (j < 512 ? bh[j] : 0.f);
    }
}

// ---------------- gi GEMM (verified round 3, source-identical) ----------------
__device__ __forceinline__ half8_t cvt8(float4 a, float4 b) {
    half8_t r;
    r[0] = (_Float16)a.x; r[1] = (_Float16)a.y; r[2] = (_Float16)a.z; r[3] = (_Float16)a.w;
    r[4] = (_Float16)b.x; r[5] = (_Float16)b.y; r[6] = (_Float16)b.z; r[7] = (_Float16)b.w;
    return r;
}

__global__ __launch_bounds__(256) void k_gemm(const float* __restrict__ x,
                                              const float* __restrict__ Wih1,
                                              const float* __restrict__ Wih2,
                                              const float* __restrict__ bias,
                                              _Float16* __restrict__ gi) {
    __shared__ __align__(16) _Float16 As[128*32];   // [m][k], LD=32
    __shared__ __align__(16) _Float16 Bs[256*32];   // [n][k], LD=32
    const int tid = threadIdx.x;
    const int m0 = blockIdx.x * 128;
    const int n0 = blockIdx.y * 256;                // 768 = 3*256: no dir straddle
    const int lane = tid & 63, wave = tid >> 6;
    const int wr = wave >> 1, wc = wave & 1;        // 2x2 waves: 64M x 128N each
    floatx4 acc[4][8];
#pragma unroll
    for (int i = 0; i < 4; ++i)
#pragma unroll
        for (int j = 0; j < 8; ++j) acc[i][j] = (floatx4)0.f;

    const float* Wsrc = (n0 < 768) ? Wih1 : Wih2;
    const int nl = (n0 < 768) ? n0 : (n0 - 768);
    const int ar = tid >> 1, ah = (tid & 1) * 16;   // A: 2 threads/row, 16 cols each
    const float* Ag = x + (size_t)(m0 + ar)*512 + ah;
    const float* Bg = Wsrc + (size_t)(nl + tid)*512; // B: 1 thread/row, 32 cols
    _Float16* Aw = As + ar*32 + ah;
    _Float16* Bw = Bs + tid*32;
    const int aoff = (wr*64  + (lane & 15))*32 + (lane >> 4)*8;
    const int boff = (wc*128 + (lane & 15))*32 + (lane >> 4)*8;

    for (int kt = 0; kt < 16; ++kt) {
        const int ko = kt*32;
        float4 a0 = *(const float4*)(Ag + ko);
        float4 a1 = *(const float4*)(Ag + ko + 4);
        float4 a2 = *(const float4*)(Ag + ko + 8);
        float4 a3 = *(const float4*)(Ag + ko + 12);
        float4 b0 = *(const float4*)(Bg + ko);
        float4 b1 = *(const float4*)(Bg + ko + 4);
        float4 b2 = *(const float4*)(Bg + ko + 8);
        float4 b3 = *(const float4*)(Bg + ko + 12);
        float4 b4 = *(const float4*)(Bg + ko + 16);
        float4 b5 = *(const float4*)(Bg + ko + 20);
        float4 b6 = *(const float4*)(Bg + ko + 24);
        float4 b7 = *(const float4*)(Bg + ko + 28);
        __syncthreads();                       // prev tile's LDS reads complete
        *(half8_t*)(Aw)      = cvt8(a0, a1);
        *(half8_t*)(Aw + 8)  = cvt8(a2, a3);
        *(half8_t*)(Bw)      = cvt8(b0, b1);
        *(half8_t*)(Bw + 8)  = cvt8(b2, b3);
        *(half8_t*)(Bw + 16) = cvt8(b4, b5);
        *(half8_t*)(Bw + 24) = cvt8(b6, b7);
        __syncthreads();
        half8_t af[4], bf[8];
#pragma unroll
        for (int f = 0; f < 4; ++f) af[f] = *(const half8_t*)(As + aoff + f*512);
#pragma unroll
        for (int f = 0; f < 8; ++f) bf[f] = *(const half8_t*)(Bs + boff + f*512);
#pragma unroll
        for (int i = 0; i < 4; ++i)
#pragma unroll
            for (int j = 0; j < 8; ++j)
                acc[i][j] = __builtin_amdgcn_mfma_f32_16x16x32_f16(af[i], bf[j], acc[i][j], 0, 0, 0);
    }
    // epilogue: +bias, f16, split into gi[dir][row][col]
#pragma unroll
    for (int i = 0; i < 4; ++i) {
#pragma unroll
        for (int j = 0; j < 8; ++j) {
            int col = n0 + wc*128 + j*16 + (lane & 15);
            float bv = bias[col];
            int dir = col >= 768;
            size_t gib = (size_t)dir * 25165824ull + (size_t)(col - dir*768);
#pragma unroll
            for (int q = 0; q < 4; ++q) {
                int row = m0 + wr*64 + i*16 + (lane >> 4)*4 + q;
                gi[gib + (size_t)row*768] = (_Float16)(acc[i][j][q] + bv);
            }
        }
    }
}

// ---------------- recurrent kernel: 1 WG per (direction, batch) sequence ----------------
// FIX: h buffer is _Float16[] with _Float16 scalar writes + half8_t vector reads
// (the idiom k_gemm proved safe). The old uint[]-object / ushort-write mix was
// strict-aliasing UB -> compiler folded all h reads to the zero-init.
#define FDOT2(w_, h_, acc_) __builtin_amdgcn_fdot2(__builtin_bit_cast(half2_t,(w_)), (h_), (acc_), false)

__global__ __launch_bounds__(512, 2) void k_rnn(const float* __restrict__ Whh1,
                                                const float* __restrict__ Whh2,
                                                const _Float16* __restrict__ gi,
                                                const float* __restrict__ mask,
                                                const float* __restrict__ bhh1,
                                                const float* __restrict__ bhh2,
                                                float* __restrict__ outp) {
    __shared__ __align__(16) _Float16 hs16[256];     // h as f16
    __shared__ float part[768];                      // kh=1 partial sums
    const int tid = threadIdx.x;
    const int bid = blockIdx.x;                      // 0..127
    const int dir = bid >> 6, b = bid & 63;
    const int c  = tid & 255;                        // column this thread owns
    const int kh = tid >> 8;                         // K half

    // W_hh rows {c, c+256, c+512}, k in [kh*128, kh*128+128), packed f16x2 in-register.
    const float* W = dir ? Whh2 : Whh1;              // (768, 256) row-major
    unsigned int w[192];
#pragma unroll
    for (int a = 0; a < 3; ++a) {
        const float* wrow = W + (size_t)(c + a*256)*256 + kh*128;
#pragma unroll
        for (int qq = 0; qq < 64; ++qq) {
            float2 f = *(const float2*)(wrow + 2*qq);
            half2_t hp = {(_Float16)f.x, (_Float16)f.y};
            w[a*64 + qq] = __builtin_bit_cast(unsigned int, hp);
        }
    }
    const float bhn = (dir ? bhh2 : bhh1)[512 + c];

    if (tid < 256) hs16[tid] = (_Float16)0.f;
    float h_c = 0.f;
    __syncthreads();

    const _Float16* gb = gi + (size_t)dir * 25165824ull + c;
    const _Float16* hrd = hs16 + (kh << 7);          // this thread's K-half base

#pragma unroll 1
    for (int s = 0; s < 512; ++s) {
        const int t = dir ? (511 - s) : s;
        float g0 = 0.f, g1 = 0.f, g2 = 0.f, mv = 0.f;
        if (tid < 256) {
            const _Float16* gp = gb + (size_t)(t*64 + b)*768;
            g0 = (float)gp[0];                       // i_r (+b_ih_r+b_hh_r folded)
            g1 = (float)gp[256];                     // i_z (+b_ih_z+b_hh_z folded)
            g2 = (float)gp[512];                     // i_n (+b_ih_n folded)
            mv = mask[t*64 + b];
        }
        // gh dot products: 3 gate rows x 128 K-values, f16x2 dot2
        float a0 = 0.f, a1 = 0.f, a2 = 0.f;
        float b0 = 0.f, b1 = 0.f, b2 = 0.f;          // second chains for ILP
#pragma unroll
        for (int kk = 0; kk < 16; ++kk) {
            half8_t hv = *(const half8_t*)(hrd + (kk << 3));  // broadcast ds_read_b128
            half2_t h0 = {hv[0], hv[1]};
            half2_t h1 = {hv[2], hv[3]};
            half2_t h2 = {hv[4], hv[5]};
            half2_t h3 = {hv[6], hv[7]};
            const int q = kk << 2;
            a0 = FDOT2(w[      q + 0], h0, a0);  b0 = FDOT2(w[      q + 1], h1, b0);
            a0 = FDOT2(w[      q + 2], h2, a0);  b0 = FDOT2(w[      q + 3], h3, b0);
            a1 = FDOT2(w[ 64 + q + 0], h0, a1);  b1 = FDOT2(w[ 64 + q + 1], h1, b1);
            a1 = FDOT2(w[ 64 + q + 2], h2, a1);  b1 = FDOT2(w[ 64 + q + 3], h3, b1);
            a2 = FDOT2(w[128 + q + 0], h0, a2);  b2 = FDOT2(w[128 + q + 1], h1, b2);
            a2 = FDOT2(w[128 + q + 2], h2, a2);  b2 = FDOT2(w[128 + q + 3], h3, b2);
        }
        a0 += b0; a1 += b1; a2 += b2;
        if (tid >= 256) { part[c] = a0; part[256 + c] = a1; part[512 + c] = a2; }
        __syncthreads();
        if (tid < 256) {
            float ghr = a0 + part[c];
            float ghz = a1 + part[256 + c];
            float ghn = a2 + part[512 + c];
            float r = 1.f / (1.f + __expf(-(g0 + ghr)));
            float z = 1.f / (1.f + __expf(-(g1 + ghz)));
            float tt = g2 + r * (ghn + bhn);
            float ea = __expf(-2.f * fabsf(tt));     // overflow-safe tanh
            float nt = (1.f - ea) / (1.f + ea);
            nt = (tt < 0.f) ? -nt : nt;
            float ht = (1.f - z) * nt + z * h_c;
            float hm = mv * ht + (1.f - mv) * h_c;
            h_c = hm;
            hs16[c] = (_Float16)hm;                  // typed f16 store (no aliasing UB)
            outp[(size_t)(t*64 + b)*512 + dir*256 + c] = mv * ht;
        }
        __syncthreads();
    }
    if (tid < 256) {
        outp[16777216u + dir*16384 + b*256 + c] = h_c;   // hidden[dir][b][c]
    }
}

// ---------------- launch ----------------
extern "C" void kernel_launch(void* const* d_in, const int* in_sizes, int n_in,
                              void* d_out, int out_size, void* d_ws, size_t ws_size,
                              hipStream_t stream) {
    const float* x    = (const float*)d_in[0];
    const float* mask = (const float*)d_in[1];
    const float* Wih1 = (const float*)d_in[2];
    const float* Whh1 = (const float*)d_in[3];
    const float* bih1 = (const float*)d_in[4];
    const float* bhh1 = (const float*)d_in[5];
    const float* Wih2 = (const float*)d_in[6];
    const float* Whh2 = (const float*)d_in[7];
    const float* bih2 = (const float*)d_in[8];
    const float* bhh2 = (const float*)d_in[9];
    char* ws = (char*)d_ws;
    float* biascat = (float*)(ws + OFF_BIAS);
    _Float16* gi   = (_Float16*)(ws + OFF_GI);
    float* outp = (float*)d_out;

    hipLaunchKernelGGL(k_prep, dim3(6), dim3(256), 0, stream,
                       bih1, bih2, bhh1, bhh2, biascat);
    hipLaunchKernelGGL(k_gemm, dim3(256, 6), dim3(256), 0, stream, x, Wih1, Wih2, biascat, gi);
    hipLaunchKernelGGL(k_rnn, dim3(128), dim3(512), 0, stream,
                       Whh1, Whh2, gi, mask, bhh1, bhh2, outp);
}

// Round 7
// 845.409 us; speedup vs baseline: 13.3336x; 1.0079x over previous
//
#include <hip/hip_runtime.h>
#include <cstdint>

typedef _Float16 half2_t __attribute__((ext_vector_type(2)));
typedef _Float16 half8_t __attribute__((ext_vector_type(8)));
typedef float    floatx4 __attribute__((ext_vector_type(4)));

// ---------------- workspace layout (bytes) ----------------
#define OFF_BIAS  0ull
#define SZ_BIAS   (1536ull*4)                  // b_ih + b_hh(r,z) folded, f32
#define OFF_GI    6144ull                      // gi f16 [2][32768][768] (~100.7 MB)

// ---------------- prep: bias fold only (verified) ----------------
__global__ void k_prep(const float* __restrict__ bih1, const float* __restrict__ bih2,
                       const float* __restrict__ bhh1, const float* __restrict__ bhh2,
                       float* __restrict__ biascat) {
    int q3 = blockIdx.x * 256 + threadIdx.x;
    if (q3 < 1536) {
        // fold b_ih (all gates) + b_hh (r,z only; n-gate's b_hh is inside r*(...))
        int dir = q3 >= 768;  int j = q3 - dir*768;
        const float* bi = dir ? bih2 : bih1;
        const float* bh = dir ? bhh2 : bhh1;
        biascat[q3] = bi[j] + (j < 512 ? bh[j] : 0.f);
    }
}

// ---------------- gi GEMM (verified, source-identical) ----------------
__device__ __forceinline__ half8_t cvt8(float4 a, float4 b) {
    half8_t r;
    r[0] = (_Float16)a.x; r[1] = (_Float16)a.y; r[2] = (_Float16)a.z; r[3] = (_Float16)a.w;
    r[4] = (_Float16)b.x; r[5] = (_Float16)b.y; r[6] = (_Float16)b.z; r[7] = (_Float16)b.w;
    return r;
}

__global__ __launch_bounds__(256) void k_gemm(const float* __restrict__ x,
                                              const float* __restrict__ Wih1,
                                              const float* __restrict__ Wih2,
                                              const float* __restrict__ bias,
                                              _Float16* __restrict__ gi) {
    __shared__ __align__(16) _Float16 As[128*32];   // [m][k], LD=32
    __shared__ __align__(16) _Float16 Bs[256*32];   // [n][k], LD=32
    const int tid = threadIdx.x;
    const int m0 = blockIdx.x * 128;
    const int n0 = blockIdx.y * 256;                // 768 = 3*256: no dir straddle
    const int lane = tid & 63, wave = tid >> 6;
    const int wr = wave >> 1, wc = wave & 1;        // 2x2 waves: 64M x 128N each
    floatx4 acc[4][8];
#pragma unroll
    for (int i = 0; i < 4; ++i)
#pragma unroll
        for (int j = 0; j < 8; ++j) acc[i][j] = (floatx4)0.f;

    const float* Wsrc = (n0 < 768) ? Wih1 : Wih2;
    const int nl = (n0 < 768) ? n0 : (n0 - 768);
    const int ar = tid >> 1, ah = (tid & 1) * 16;   // A: 2 threads/row, 16 cols each
    const float* Ag = x + (size_t)(m0 + ar)*512 + ah;
    const float* Bg = Wsrc + (size_t)(nl + tid)*512; // B: 1 thread/row, 32 cols
    _Float16* Aw = As + ar*32 + ah;
    _Float16* Bw = Bs + tid*32;
    const int aoff = (wr*64  + (lane & 15))*32 + (lane >> 4)*8;
    const int boff = (wc*128 + (lane & 15))*32 + (lane >> 4)*8;

    for (int kt = 0; kt < 16; ++kt) {
        const int ko = kt*32;
        float4 a0 = *(const float4*)(Ag + ko);
        float4 a1 = *(const float4*)(Ag + ko + 4);
        float4 a2 = *(const float4*)(Ag + ko + 8);
        float4 a3 = *(const float4*)(Ag + ko + 12);
        float4 b0 = *(const float4*)(Bg + ko);
        float4 b1 = *(const float4*)(Bg + ko + 4);
        float4 b2 = *(const float4*)(Bg + ko + 8);
        float4 b3 = *(const float4*)(Bg + ko + 12);
        float4 b4 = *(const float4*)(Bg + ko + 16);
        float4 b5 = *(const float4*)(Bg + ko + 20);
        float4 b6 = *(const float4*)(Bg + ko + 24);
        float4 b7 = *(const float4*)(Bg + ko + 28);
        __syncthreads();                       // prev tile's LDS reads complete
        *(half8_t*)(Aw)      = cvt8(a0, a1);
        *(half8_t*)(Aw + 8)  = cvt8(a2, a3);
        *(half8_t*)(Bw)      = cvt8(b0, b1);
        *(half8_t*)(Bw + 8)  = cvt8(b2, b3);
        *(half8_t*)(Bw + 16) = cvt8(b4, b5);
        *(half8_t*)(Bw + 24) = cvt8(b6, b7);
        __syncthreads();
        half8_t af[4], bf[8];
#pragma unroll
        for (int f = 0; f < 4; ++f) af[f] = *(const half8_t*)(As + aoff + f*512);
#pragma unroll
        for (int f = 0; f < 8; ++f) bf[f] = *(const half8_t*)(Bs + boff + f*512);
#pragma unroll
        for (int i = 0; i < 4; ++i)
#pragma unroll
            for (int j = 0; j < 8; ++j)
                acc[i][j] = __builtin_amdgcn_mfma_f32_16x16x32_f16(af[i], bf[j], acc[i][j], 0, 0, 0);
    }
    // epilogue: +bias, f16, split into gi[dir][row][col]
#pragma unroll
    for (int i = 0; i < 4; ++i) {
#pragma unroll
        for (int j = 0; j < 8; ++j) {
            int col = n0 + wc*128 + j*16 + (lane & 15);
            float bv = bias[col];
            int dir = col >= 768;
            size_t gib = (size_t)dir * 25165824ull + (size_t)(col - dir*768);
#pragma unroll
            for (int q = 0; q < 4; ++q) {
                int row = m0 + wr*64 + i*16 + (lane >> 4)*4 + q;
                gi[gib + (size_t)row*768] = (_Float16)(acc[i][j][q] + bv);
            }
        }
    }
}

// ---------------- recurrent kernel: 1 WG per (direction, batch) sequence ----------------
// R7: launch_bounds(512,1) -> 256 VGPR budget (kills the w[192] spill that
// launch_bounds(512,2)/128-VGPR forced), raw lgkm-only barriers (no vmcnt(0)
// store-ack drain on the critical path).
#define FDOT2(w_, h_, acc_) __builtin_amdgcn_fdot2(__builtin_bit_cast(half2_t,(w_)), (h_), (acc_), false)
#define LBAR()  do { asm volatile("s_waitcnt lgkmcnt(0)" ::: "memory"); \
                     __builtin_amdgcn_s_barrier(); } while (0)

__global__ __launch_bounds__(512, 1) void k_rnn(const float* __restrict__ Whh1,
                                                const float* __restrict__ Whh2,
                                                const _Float16* __restrict__ gi,
                                                const float* __restrict__ mask,
                                                const float* __restrict__ bhh1,
                                                const float* __restrict__ bhh2,
                                                float* __restrict__ outp) {
    __shared__ __align__(16) _Float16 hs16[256];     // h as f16
    __shared__ float part[768];                      // kh=1 partial sums
    const int tid = threadIdx.x;
    const int bid = blockIdx.x;                      // 0..127
    const int dir = bid >> 6, b = bid & 63;
    const int c  = tid & 255;                        // column this thread owns
    const int kh = tid >> 8;                         // K half

    // W_hh rows {c, c+256, c+512}, k in [kh*128, kh*128+128), packed f16x2 in-register.
    const float* W = dir ? Whh2 : Whh1;              // (768, 256) row-major
    unsigned int w[192];
#pragma unroll
    for (int a = 0; a < 3; ++a) {
        const float* wrow = W + (size_t)(c + a*256)*256 + kh*128;
#pragma unroll
        for (int qq = 0; qq < 64; ++qq) {
            float2 f = *(const float2*)(wrow + 2*qq);
            half2_t hp = {(_Float16)f.x, (_Float16)f.y};
            w[a*64 + qq] = __builtin_bit_cast(unsigned int, hp);
        }
    }
    const float bhn = (dir ? bhh2 : bhh1)[512 + c];

    if (tid < 256) hs16[tid] = (_Float16)0.f;
    float h_c = 0.f;
    __syncthreads();

    const _Float16* gb = gi + (size_t)dir * 25165824ull + c;
    const _Float16* hrd = hs16 + (kh << 7);          // this thread's K-half base

#pragma unroll 1
    for (int s = 0; s < 512; ++s) {
        const int t = dir ? (511 - s) : s;
        float g0 = 0.f, g1 = 0.f, g2 = 0.f, mv = 0.f;
        if (tid < 256) {
            // issued here, consumed after barrier 1 -> ~1 dot-phase of latency cover
            const _Float16* gp = gb + (size_t)(t*64 + b)*768;
            g0 = (float)gp[0];                       // i_r (+b_ih_r+b_hh_r folded)
            g1 = (float)gp[256];                     // i_z (+b_ih_z+b_hh_z folded)
            g2 = (float)gp[512];                     // i_n (+b_ih_n folded)
            mv = mask[t*64 + b];
        }
        // gh dot products: 3 gate rows x 128 K-values, f16x2 dot2
        float a0 = 0.f, a1 = 0.f, a2 = 0.f;
        float b0 = 0.f, b1 = 0.f, b2 = 0.f;          // second chains for ILP
#pragma unroll
        for (int kk = 0; kk < 16; ++kk) {
            half8_t hv = *(const half8_t*)(hrd + (kk << 3));  // broadcast ds_read_b128
            half2_t h0 = {hv[0], hv[1]};
            half2_t h1 = {hv[2], hv[3]};
            half2_t h2 = {hv[4], hv[5]};
            half2_t h3 = {hv[6], hv[7]};
            const int q = kk << 2;
            a0 = FDOT2(w[      q + 0], h0, a0);  b0 = FDOT2(w[      q + 1], h1, b0);
            a0 = FDOT2(w[      q + 2], h2, a0);  b0 = FDOT2(w[      q + 3], h3, b0);
            a1 = FDOT2(w[ 64 + q + 0], h0, a1);  b1 = FDOT2(w[ 64 + q + 1], h1, b1);
            a1 = FDOT2(w[ 64 + q + 2], h2, a1);  b1 = FDOT2(w[ 64 + q + 3], h3, b1);
            a2 = FDOT2(w[128 + q + 0], h0, a2);  b2 = FDOT2(w[128 + q + 1], h1, b2);
            a2 = FDOT2(w[128 + q + 2], h2, a2);  b2 = FDOT2(w[128 + q + 3], h3, b2);
        }
        a0 += b0; a1 += b1; a2 += b2;
        if (tid >= 256) { part[c] = a0; part[256 + c] = a1; part[512 + c] = a2; }
        LBAR();                                      // part visible; hs16 reads done
        if (tid < 256) {
            float ghr = a0 + part[c];
            float ghz = a1 + part[256 + c];
            float ghn = a2 + part[512 + c];
            float r = 1.f / (1.f + __expf(-(g0 + ghr)));
            float z = 1.f / (1.f + __expf(-(g1 + ghz)));
            float tt = g2 + r * (ghn + bhn);
            float ea = __expf(-2.f * fabsf(tt));     // overflow-safe tanh
            float nt = (1.f - ea) / (1.f + ea);
            nt = (tt < 0.f) ? -nt : nt;
            float ht = (1.f - z) * nt + z * h_c;
            float hm = mv * ht + (1.f - mv) * h_c;
            h_c = hm;
            hs16[c] = (_Float16)hm;                  // typed f16 store
            outp[(size_t)(t*64 + b)*512 + dir*256 + c] = mv * ht;  // ack never drained
        }
        LBAR();                                      // hs16 visible for next step
    }
    if (tid < 256) {
        outp[16777216u + dir*16384 + b*256 + c] = h_c;   // hidden[dir][b][c]
    }
}

// ---------------- launch ----------------
extern "C" void kernel_launch(void* const* d_in, const int* in_sizes, int n_in,
                              void* d_out, int out_size, void* d_ws, size_t ws_size,
                              hipStream_t stream) {
    const float* x    = (const float*)d_in[0];
    const float* mask = (const float*)d_in[1];
    const float* Wih1 = (const float*)d_in[2];
    const float* Whh1 = (const float*)d_in[3];
    const float* bih1 = (const float*)d_in[4];
    const float* bhh1 = (const float*)d_in[5];
    const float* Wih2 = (const float*)d_in[6];
    const float* Whh2 = (const float*)d_in[7];
    const float* bih2 = (const float*)d_in[8];
    const float* bhh2 = (const float*)d_in[9];
    char* ws = (char*)d_ws;
    float* biascat = (float*)(ws + OFF_BIAS);
    _Float16* gi   = (_Float16*)(ws + OFF_GI);
    float* outp = (float*)d_out;

    hipLaunchKernelGGL(k_prep, dim3(6), dim3(256), 0, stream,
                       bih1, bih2, bhh1, bhh2, biascat);
    hipLaunchKernelGGL(k_gemm, dim3(256, 6), dim3(256), 0, stream, x, Wih1, Wih2, biascat, gi);
    hipLaunchKernelGGL(k_rnn, dim3(128), dim3(512), 0, stream,
                       Whh1, Whh2, gi, mask, bhh1, bhh2, outp);
}

// Round 9
// 841.244 us; speedup vs baseline: 13.3996x; 1.0050x over previous
//
#include <hip/hip_runtime.h>
#include <cstdint>

typedef _Float16 half2_t __attribute__((ext_vector_type(2)));
typedef _Float16 half8_t __attribute__((ext_vector_type(8)));
typedef float    floatx4 __attribute__((ext_vector_type(4)));

// ---------------- workspace layout (bytes) ----------------
#define OFF_BIAS  0ull
#define SZ_BIAS   (1536ull*4)                  // b_ih + b_hh(r,z) folded, f32
#define OFF_GI    6144ull                      // gi f16 [2][32768][768] (~100.7 MB)

// ---------------- prep: bias fold only (verified) ----------------
__global__ void k_prep(const float* __restrict__ bih1, const float* __restrict__ bih2,
                       const float* __restrict__ bhh1, const float* __restrict__ bhh2,
                       float* __restrict__ biascat) {
    int q3 = blockIdx.x * 256 + threadIdx.x;
    if (q3 < 1536) {
        // fold b_ih (all gates) + b_hh (r,z only; n-gate's b_hh is inside r*(...))
        int dir = q3 >= 768;  int j = q3 - dir*768;
        const float* bi = dir ? bih2 : bih1;
        const float* bh = dir ? bhh2 : bhh1;
        biascat[q3] = bi[j] + (j < 512 ? bh[j] : 0.f);
    }
}

// ---------------- shared helper (verified in k_gemm since round 3) ----------------
__device__ __forceinline__ half8_t cvt8(float4 a, float4 b) {
    half8_t r;
    r[0] = (_Float16)a.x; r[1] = (_Float16)a.y; r[2] = (_Float16)a.z; r[3] = (_Float16)a.w;
    r[4] = (_Float16)b.x; r[5] = (_Float16)b.y; r[6] = (_Float16)b.z; r[7] = (_Float16)b.w;
    return r;
}

// ---------------- gi GEMM (verified, source-identical) ----------------
__global__ __launch_bounds__(256) void k_gemm(const float* __restrict__ x,
                                              const float* __restrict__ Wih1,
                                              const float* __restrict__ Wih2,
                                              const float* __restrict__ bias,
                                              _Float16* __restrict__ gi) {
    __shared__ __align__(16) _Float16 As[128*32];   // [m][k], LD=32
    __shared__ __align__(16) _Float16 Bs[256*32];   // [n][k], LD=32
    const int tid = threadIdx.x;
    const int m0 = blockIdx.x * 128;
    const int n0 = blockIdx.y * 256;                // 768 = 3*256: no dir straddle
    const int lane = tid & 63, wave = tid >> 6;
    const int wr = wave >> 1, wc = wave & 1;        // 2x2 waves: 64M x 128N each
    floatx4 acc[4][8];
#pragma unroll
    for (int i = 0; i < 4; ++i)
#pragma unroll
        for (int j = 0; j < 8; ++j) acc[i][j] = (floatx4)0.f;

    const float* Wsrc = (n0 < 768) ? Wih1 : Wih2;
    const int nl = (n0 < 768) ? n0 : (n0 - 768);
    const int ar = tid >> 1, ah = (tid & 1) * 16;   // A: 2 threads/row, 16 cols each
    const float* Ag = x + (size_t)(m0 + ar)*512 + ah;
    const float* Bg = Wsrc + (size_t)(nl + tid)*512; // B: 1 thread/row, 32 cols
    _Float16* Aw = As + ar*32 + ah;
    _Float16* Bw = Bs + tid*32;
    const int aoff = (wr*64  + (lane & 15))*32 + (lane >> 4)*8;
    const int boff = (wc*128 + (lane & 15))*32 + (lane >> 4)*8;

    for (int kt = 0; kt < 16; ++kt) {
        const int ko = kt*32;
        float4 a0 = *(const float4*)(Ag + ko);
        float4 a1 = *(const float4*)(Ag + ko + 4);
        float4 a2 = *(const float4*)(Ag + ko + 8);
        float4 a3 = *(const float4*)(Ag + ko + 12);
        float4 b0 = *(const float4*)(Bg + ko);
        float4 b1 = *(const float4*)(Bg + ko + 4);
        float4 b2 = *(const float4*)(Bg + ko + 8);
        float4 b3 = *(const float4*)(Bg + ko + 12);
        float4 b4 = *(const float4*)(Bg + ko + 16);
        float4 b5 = *(const float4*)(Bg + ko + 20);
        float4 b6 = *(const float4*)(Bg + ko + 24);
        float4 b7 = *(const float4*)(Bg + ko + 28);
        __syncthreads();                       // prev tile's LDS reads complete
        *(half8_t*)(Aw)      = cvt8(a0, a1);
        *(half8_t*)(Aw + 8)  = cvt8(a2, a3);
        *(half8_t*)(Bw)      = cvt8(b0, b1);
        *(half8_t*)(Bw + 8)  = cvt8(b2, b3);
        *(half8_t*)(Bw + 16) = cvt8(b4, b5);
        *(half8_t*)(Bw + 24) = cvt8(b6, b7);
        __syncthreads();
        half8_t af[4], bf[8];
#pragma unroll
        for (int f = 0; f < 4; ++f) af[f] = *(const half8_t*)(As + aoff + f*512);
#pragma unroll
        for (int f = 0; f < 8; ++f) bf[f] = *(const half8_t*)(Bs + boff + f*512);
#pragma unroll
        for (int i = 0; i < 4; ++i)
#pragma unroll
            for (int j = 0; j < 8; ++j)
                acc[i][j] = __builtin_amdgcn_mfma_f32_16x16x32_f16(af[i], bf[j], acc[i][j], 0, 0, 0);
    }
    // epilogue: +bias, f16, split into gi[dir][row][col]
#pragma unroll
    for (int i = 0; i < 4; ++i) {
#pragma unroll
        for (int j = 0; j < 8; ++j) {
            int col = n0 + wc*128 + j*16 + (lane & 15);
            float bv = bias[col];
            int dir = col >= 768;
            size_t gib = (size_t)dir * 25165824ull + (size_t)(col - dir*768);
#pragma unroll
            for (int q = 0; q < 4; ++q) {
                int row = m0 + wr*64 + i*16 + (lane >> 4)*4 + q;
                gi[gib + (size_t)row*768] = (_Float16)(acc[i][j][q] + bv);
            }
        }
    }
}

// ---------------- recurrent kernel: 1 WG per (direction, batch) sequence ----------------
// R9: W file = 48 NAMED half8_t (k_gemm's proven type), init via float4+cvt8
// (proven), pair-extraction {v[2j],v[2j+1]} (proven on the h side). No arrays
// -> nothing for the allocator to demote to scratch. Body otherwise R7-exact.
#define FDOT2v(wp_, h_, acc_) __builtin_amdgcn_fdot2((wp_), (h_), (acc_), false)
#define LBAR()  do { asm volatile("s_waitcnt lgkmcnt(0)" ::: "memory"); \
                     __builtin_amdgcn_s_barrier(); } while (0)

#define WLOAD(p_) cvt8(*(const float4*)(p_), *(const float4*)((p_) + 4))

#define DECL_ROW(P_, rp_) \
    half8_t P_##0  = WLOAD(rp_ +   0), P_##1  = WLOAD(rp_ +   8), \
            P_##2  = WLOAD(rp_ +  16), P_##3  = WLOAD(rp_ +  24), \
            P_##4  = WLOAD(rp_ +  32), P_##5  = WLOAD(rp_ +  40), \
            P_##6  = WLOAD(rp_ +  48), P_##7  = WLOAD(rp_ +  56), \
            P_##8  = WLOAD(rp_ +  64), P_##9  = WLOAD(rp_ +  72), \
            P_##10 = WLOAD(rp_ +  80), P_##11 = WLOAD(rp_ +  88), \
            P_##12 = WLOAD(rp_ +  96), P_##13 = WLOAD(rp_ + 104), \
            P_##14 = WLOAD(rp_ + 112), P_##15 = WLOAD(rp_ + 120);

// one f16x2 pair from a half8_t (pairs sit exactly on VGPR boundaries)
#define FD(wv_, j_, hp_, acc_) do { \
    half2_t wp_ = {(wv_)[2*(j_)], (wv_)[2*(j_)+1]}; \
    acc_ = FDOT2v(wp_, (hp_), (acc_)); } while (0)

// one K-octet: h broadcast + 12 fdot2 (4 pairs x 3 gates)
#define DOTK(wrv_, wzv_, wnv_, kk_) do { \
    half8_t hv_ = *(const half8_t*)(hrd + ((kk_) << 3)); \
    half2_t h0_ = {hv_[0], hv_[1]}, h1_ = {hv_[2], hv_[3]}; \
    half2_t h2_ = {hv_[4], hv_[5]}, h3_ = {hv_[6], hv_[7]}; \
    FD(wrv_,0,h0_,a0); FD(wrv_,1,h1_,b0); FD(wrv_,2,h2_,a0); FD(wrv_,3,h3_,b0); \
    FD(wzv_,0,h0_,a1); FD(wzv_,1,h1_,b1); FD(wzv_,2,h2_,a1); FD(wzv_,3,h3_,b1); \
    FD(wnv_,0,h0_,a2); FD(wnv_,1,h1_,b2); FD(wnv_,2,h2_,a2); FD(wnv_,3,h3_,b2); \
} while (0)

__global__ __launch_bounds__(512) __attribute__((amdgpu_waves_per_eu(2, 2)))
void k_rnn(const float* __restrict__ Whh1,
           const float* __restrict__ Whh2,
           const _Float16* __restrict__ gi,
           const float* __restrict__ mask,
           const float* __restrict__ bhh1,
           const float* __restrict__ bhh2,
           float* __restrict__ outp) {
    __shared__ __align__(16) _Float16 hs16[256];     // h as f16
    __shared__ float part[768];                      // kh=1 partial sums
    const int tid = threadIdx.x;
    const int bid = blockIdx.x;                      // 0..127
    const int dir = bid >> 6, b = bid & 63;
    const int c  = tid & 255;                        // column this thread owns
    const int kh = tid >> 8;                         // K half

    // W_hh rows {c, c+256, c+512}, K-half kh: 48 named half8_t = 192 VGPRs
    const float* W  = dir ? Whh2 : Whh1;             // (768, 256) row-major
    const float* r0 = W + (size_t)c*256 + kh*128;
    const float* r1 = W + (size_t)(c + 256)*256 + kh*128;
    const float* r2 = W + (size_t)(c + 512)*256 + kh*128;
    DECL_ROW(wr, r0)                                 // r-gate: wr0..wr15
    DECL_ROW(wz, r1)                                 // z-gate: wz0..wz15
    DECL_ROW(wn, r2)                                 // n-gate: wn0..wn15
    const float bhn = (dir ? bhh2 : bhh1)[512 + c];

    if (tid < 256) hs16[tid] = (_Float16)0.f;
    float h_c = 0.f;
    __syncthreads();

    const _Float16* gb = gi + (size_t)dir * 25165824ull + c;
    const _Float16* hrd = hs16 + (kh << 7);          // this thread's K-half base

#pragma unroll 1
    for (int s = 0; s < 512; ++s) {
        const int t = dir ? (511 - s) : s;
        float g0 = 0.f, g1 = 0.f, g2 = 0.f, mv = 0.f;
        if (tid < 256) {
            // issued here, consumed after barrier 1 -> dot phase covers latency
            const _Float16* gp = gb + (size_t)(t*64 + b)*768;
            g0 = (float)gp[0];                       // i_r (+b_ih_r+b_hh_r folded)
            g1 = (float)gp[256];                     // i_z (+b_ih_z+b_hh_z folded)
            g2 = (float)gp[512];                     // i_n (+b_ih_n folded)
            mv = mask[t*64 + b];
        }
        // gh dot products: 3 gate rows x 128 K-values, f16x2 dot2
        float a0 = 0.f, a1 = 0.f, a2 = 0.f;
        float b0 = 0.f, b1 = 0.f, b2 = 0.f;          // second chains for ILP
        DOTK(wr0,  wz0,  wn0,  0);   DOTK(wr1,  wz1,  wn1,  1);
        DOTK(wr2,  wz2,  wn2,  2);   DOTK(wr3,  wz3,  wn3,  3);
        DOTK(wr4,  wz4,  wn4,  4);   DOTK(wr5,  wz5,  wn5,  5);
        DOTK(wr6,  wz6,  wn6,  6);   DOTK(wr7,  wz7,  wn7,  7);
        DOTK(wr8,  wz8,  wn8,  8);   DOTK(wr9,  wz9,  wn9,  9);
        DOTK(wr10, wz10, wn10, 10);  DOTK(wr11, wz11, wn11, 11);
        DOTK(wr12, wz12, wn12, 12);  DOTK(wr13, wz13, wn13, 13);
        DOTK(wr14, wz14, wn14, 14);  DOTK(wr15, wz15, wn15, 15);
        a0 += b0; a1 += b1; a2 += b2;
        if (tid >= 256) { part[c] = a0; part[256 + c] = a1; part[512 + c] = a2; }
        LBAR();                                      // part visible; hs16 reads done
        if (tid < 256) {
            float ghr = a0 + part[c];
            float ghz = a1 + part[256 + c];
            float ghn = a2 + part[512 + c];
            float r = 1.f / (1.f + __expf(-(g0 + ghr)));
            float z = 1.f / (1.f + __expf(-(g1 + ghz)));
            float tt = g2 + r * (ghn + bhn);
            float ea = __expf(-2.f * fabsf(tt));     // overflow-safe tanh
            float nt = (1.f - ea) / (1.f + ea);
            nt = (tt < 0.f) ? -nt : nt;
            float ht = (1.f - z) * nt + z * h_c;
            float hm = mv * ht + (1.f - mv) * h_c;
            h_c = hm;
            hs16[c] = (_Float16)hm;                  // typed f16 store
            outp[(size_t)(t*64 + b)*512 + dir*256 + c] = mv * ht;  // ack never drained
        }
        LBAR();                                      // hs16 visible for next step
    }
    if (tid < 256) {
        outp[16777216u + dir*16384 + b*256 + c] = h_c;   // hidden[dir][b][c]
    }
}

// ---------------- launch ----------------
extern "C" void kernel_launch(void* const* d_in, const int* in_sizes, int n_in,
                              void* d_out, int out_size, void* d_ws, size_t ws_size,
                              hipStream_t stream) {
    const float* x    = (const float*)d_in[0];
    const float* mask = (const float*)d_in[1];
    const float* Wih1 = (const float*)d_in[2];
    const float* Whh1 = (const float*)d_in[3];
    const float* bih1 = (const float*)d_in[4];
    const float* bhh1 = (const float*)d_in[5];
    const float* Wih2 = (const float*)d_in[6];
    const float* Whh2 = (const float*)d_in[7];
    const float* bih2 = (const float*)d_in[8];
    const float* bhh2 = (const float*)d_in[9];
    char* ws = (char*)d_ws;
    float* biascat = (float*)(ws + OFF_BIAS);
    _Float16* gi   = (_Float16*)(ws + OFF_GI);
    float* outp = (float*)d_out;

    hipLaunchKernelGGL(k_prep, dim3(6), dim3(256), 0, stream,
                       bih1, bih2, bhh1, bhh2, biascat);
    hipLaunchKernelGGL(k_gemm, dim3(256, 6), dim3(256), 0, stream, x, Wih1, Wih2, biascat, gi);
    hipLaunchKernelGGL(k_rnn, dim3(128), dim3(512), 0, stream,
                       Whh1, Whh2, gi, mask, bhh1, bhh2, outp);
}